// Round 3
// baseline (342.915 us; speedup 1.0000x reference)
//
#include <hip/hip_runtime.h>

#define N_NODES 100000
#define E_EDGES 600000
#define LATDIM 128
#define HEAD 4
#define HDIM 32

#define SCAN_CHUNK 1024
#define SCAN_NB ((N_NODES + SCAN_CHUNK - 1) / SCAN_CHUNK)   // 98

typedef __bf16 bf16x8 __attribute__((ext_vector_type(8)));
typedef float  f32x4  __attribute__((ext_vector_type(4)));

__device__ __forceinline__ unsigned f32_to_bf16_rne(float x) {
    unsigned u = __float_as_uint(x);
    u += 0x7fffu + ((u >> 16) & 1u);   // round to nearest even
    return u >> 16;
}

__device__ __forceinline__ void bf16_split(float x, unsigned& hi, unsigned& lo) {
    unsigned hb = f32_to_bf16_rne(x);
    float hf = __uint_as_float(hb << 16);
    unsigned lb = f32_to_bf16_rne(x - hf);
    hi = hb; lo = lb;
}

// ---------------------------------------------------------------------------
// Weight prep: W[k][c] f32 -> WT_hi/WT_lo[m][c][k] bf16 (split precision).
// ---------------------------------------------------------------------------
__global__ __launch_bounds__(256) void wprep_kernel(
    const float* __restrict__ qT, const float* __restrict__ kT,
    const float* __restrict__ vT,
    unsigned short* __restrict__ WThi, unsigned short* __restrict__ WTlo)
{
    int g = blockIdx.x * 256 + threadIdx.x;      // 0..3071
    if (g >= 3072) return;
    int m    = g >> 10;          // 0..2
    int rem  = g & 1023;
    int c    = rem >> 3;         // 0..127
    int k0   = (rem & 7) * 16;   // 0..112
    const float* W = (m == 0) ? qT : (m == 1) ? kT : vT;

    unsigned short hi[16], lo[16];
    #pragma unroll
    for (int j = 0; j < 16; ++j) {
        float x = W[(size_t)(k0 + j) * 128 + c];
        unsigned hb, lb;
        bf16_split(x, hb, lb);
        hi[j] = (unsigned short)hb;
        lo[j] = (unsigned short)lb;
    }
    size_t off = (size_t)m * 16384 + (size_t)c * 128 + k0;
    *(uint4*)(WThi + off)     = *(const uint4*)&hi[0];
    *(uint4*)(WThi + off + 8) = *(const uint4*)&hi[8];
    *(uint4*)(WTlo + off)     = *(const uint4*)&lo[0];
    *(uint4*)(WTlo + off + 8) = *(const uint4*)&lo[8];
}

// ---------------------------------------------------------------------------
// Kernel A (MFMA): fused per-node Q/K/V transform via 16x16x32 bf16 MFMA with
// split-precision (hi+lo) operands: a*b ~= ah*bh + al*bh + ah*bl  (fp32-level).
// v3: T14 async-STAGE pipeline for B panels — issue next panel's global
// loads into regs at the top of the current panel's MFMA phase; ds_write
// them after the post-MFMA barrier. L2 latency leaves the critical path.
// B is single-buffered (32 KiB), total LDS stays 64 KiB -> 2 blocks/CU.
// ---------------------------------------------------------------------------
__global__ __launch_bounds__(256, 2) void qkv_mfma_kernel(
    const float* __restrict__ embeds,
    const unsigned short* __restrict__ WThi,
    const unsigned short* __restrict__ WTlo,
    float* __restrict__ Q, unsigned* __restrict__ KV)
{
    __shared__ __align__(16) char smem[65536];
    char* Ahi = smem;              // 16 KiB: 64 rows x 256B
    char* Alo = smem + 16384;
    char* Bhi = smem + 32768;      // 16 KiB: 64 cols x 256B (single-buffered)
    char* Blo = smem + 49152;

    const int tid = threadIdx.x;
    const int rowBase = blockIdx.x * 64;

    // ---- prefetch B(panel 0) into regs (overlaps whole A-stage) ----
    uint4 pbh[4], pbl[4];
    {
        const char* srch = (const char*)WThi;   // p=0: m=0,h=0
        const char* srcl = (const char*)WTlo;
        #pragma unroll
        for (int it = 0; it < 4; ++it) {
            int idx = it * 256 + tid;
            pbh[it] = *(const uint4*)(srch + idx * 16);
            pbl[it] = *(const uint4*)(srcl + idx * 16);
        }
    }

    // ---- stage A: load embeds f32, split to bf16 hi/lo, swizzled LDS ----
    #pragma unroll
    for (int it = 0; it < 8; ++it) {
        int idx = it * 256 + tid;          // 0..2047 float4 chunks
        int r  = idx >> 5;                 // 0..63
        int c4 = idx & 31;                 // 0..31
        int gr = rowBase + r;
        float4 v = make_float4(0.f, 0.f, 0.f, 0.f);
        if (gr < N_NODES) v = ((const float4*)embeds)[(size_t)gr * 32 + c4];
        unsigned hx, lx, hy, ly, hz, lz, hw, lw;
        bf16_split(v.x, hx, lx); bf16_split(v.y, hy, ly);
        bf16_split(v.z, hz, lz); bf16_split(v.w, hw, lw);
        uint2 hp = make_uint2(hx | (hy << 16), hz | (hw << 16));
        uint2 lp = make_uint2(lx | (ly << 16), lz | (lw << 16));
        int byte = r * 256 + c4 * 8;
        int swz  = byte ^ ((r & 7) << 4);
        *(uint2*)(Ahi + swz) = hp;
        *(uint2*)(Alo + swz) = lp;
    }
    __syncthreads();

    const int lane = tid & 63;
    const int wv   = tid >> 6;         // 0..3 (wave -> 16-row tile)
    const int lrow = lane & 15;
    const int kg   = lane >> 4;        // 0..3 (k-group of MFMA operand)
    const int arow = wv * 16 + lrow;   // 0..63

    // ---- write B0 to LDS; hoist A fragments in the same phase ----
    #pragma unroll
    for (int it = 0; it < 4; ++it) {
        int idx  = it * 256 + tid;
        int cl   = idx >> 4;
        int swz  = (cl * 256 + (idx & 15) * 16) ^ ((cl & 7) << 4);
        *(uint4*)(Bhi + swz) = pbh[it];
        *(uint4*)(Blo + swz) = pbl[it];
    }

    bf16x8 a_hi[4], a_lo[4];
    #pragma unroll
    for (int kk = 0; kk < 4; ++kk) {
        int byte = arow * 256 + kk * 64 + kg * 16;
        int swz  = byte ^ ((lrow & 7) << 4);     // (arow&7)==(lrow&7)
        a_hi[kk] = __builtin_bit_cast(bf16x8, *(const uint4*)(Ahi + swz));
        a_lo[kk] = __builtin_bit_cast(bf16x8, *(const uint4*)(Alo + swz));
    }
    __syncthreads();

    const int orow = kg << 2;   // C/D row base within 16-row tile (m89 layout)

    f32x4 kreg[4];

    #pragma unroll
    for (int p = 0; p < 6; ++p) {          // panel p = h*3 + m
        const int h = p / 3;
        const int m = p % 3;

        // ---- issue NEXT panel's global loads (hidden under MFMA) ----
        if (p < 5) {
            const int hn = (p + 1) / 3, mn = (p + 1) % 3;
            const char* srch = (const char*)(WThi + (size_t)mn * 16384 + (size_t)hn * 8192);
            const char* srcl = (const char*)(WTlo + (size_t)mn * 16384 + (size_t)hn * 8192);
            #pragma unroll
            for (int it = 0; it < 4; ++it) {
                int idx = it * 256 + tid;
                pbh[it] = *(const uint4*)(srch + idx * 16);
                pbl[it] = *(const uint4*)(srcl + idx * 16);
            }
        }

        // ---- MFMA on current panel ----
        f32x4 acc[4] = { {0.f,0.f,0.f,0.f}, {0.f,0.f,0.f,0.f},
                         {0.f,0.f,0.f,0.f}, {0.f,0.f,0.f,0.f} };
        #pragma unroll
        for (int kk = 0; kk < 4; ++kk) {
            #pragma unroll
            for (int n = 0; n < 4; ++n) {
                int brow = n * 16 + lrow;
                int byte = brow * 256 + kk * 64 + kg * 16;
                int swz  = byte ^ ((lrow & 7) << 4);   // (brow&7)==(lrow&7)
                bf16x8 bh = __builtin_bit_cast(bf16x8, *(const uint4*)(Bhi + swz));
                bf16x8 bl = __builtin_bit_cast(bf16x8, *(const uint4*)(Blo + swz));
                acc[n] = __builtin_amdgcn_mfma_f32_16x16x32_bf16(a_hi[kk], bh, acc[n], 0, 0, 0);
                acc[n] = __builtin_amdgcn_mfma_f32_16x16x32_bf16(a_lo[kk], bh, acc[n], 0, 0, 0);
                acc[n] = __builtin_amdgcn_mfma_f32_16x16x32_bf16(a_hi[kk], bl, acc[n], 0, 0, 0);
            }
        }

        // ---- output ----
        if (m == 0) {
            #pragma unroll
            for (int n = 0; n < 4; ++n)
                #pragma unroll
                for (int j = 0; j < 4; ++j) {
                    int gr  = rowBase + wv * 16 + orow + j;
                    int col = h * 64 + n * 16 + lrow;
                    if (gr < N_NODES) Q[(size_t)gr * 128 + col] = acc[n][j];
                }
        } else if (m == 1) {
            #pragma unroll
            for (int n = 0; n < 4; ++n) kreg[n] = acc[n];
        } else {
            #pragma unroll
            for (int n = 0; n < 4; ++n)
                #pragma unroll
                for (int j = 0; j < 4; ++j) {
                    int gr  = rowBase + wv * 16 + orow + j;
                    int col = h * 64 + n * 16 + lrow;
                    if (gr < N_NODES) {
                        unsigned pk = f32_to_bf16_rne(kreg[n][j])
                                    | (f32_to_bf16_rne(acc[n][j]) << 16);
                        KV[(size_t)gr * 128 + col] = pk;
                    }
                }
        }

        // ---- write-late: commit prefetched B(p+1) after readers drain ----
        if (p < 5) {
            __syncthreads();                 // all waves done reading B(p)
            #pragma unroll
            for (int it = 0; it < 4; ++it) { // vmcnt wait lands here
                int idx  = it * 256 + tid;
                int cl   = idx >> 4;
                int swz  = (cl * 256 + (idx & 15) * 16) ^ ((cl & 7) << 4);
                *(uint4*)(Bhi + swz) = pbh[it];
                *(uint4*)(Blo + swz) = pbl[it];
            }
            __syncthreads();                 // B(p+1) ready
        }
    }
}

// ---------------------------------------------------------------------------
// CSR build: histogram -> exclusive scan -> scatter (stores COLS directly)
// ---------------------------------------------------------------------------
__global__ __launch_bounds__(256) void hist_kernel(
    const int* __restrict__ rows, int* __restrict__ counts)
{
    int e = blockIdx.x * 256 + threadIdx.x;
    if (e < E_EDGES) atomicAdd(&counts[rows[e]], 1);
}

__global__ __launch_bounds__(256) void scan1_kernel(
    const int* __restrict__ counts, int* __restrict__ starts,
    int* __restrict__ blockSums)
{
    __shared__ int s[256];
    int b = blockIdx.x, t = threadIdx.x;
    int base = b * SCAN_CHUNK + t * 4;
    int v0 = (base + 0 < N_NODES) ? counts[base + 0] : 0;
    int v1 = (base + 1 < N_NODES) ? counts[base + 1] : 0;
    int v2 = (base + 2 < N_NODES) ? counts[base + 2] : 0;
    int v3 = (base + 3 < N_NODES) ? counts[base + 3] : 0;
    int local = v0 + v1 + v2 + v3;
    s[t] = local;
    __syncthreads();
    for (int off = 1; off < 256; off <<= 1) {
        int x = (t >= off) ? s[t - off] : 0;
        __syncthreads();
        s[t] += x;
        __syncthreads();
    }
    int incl = s[t];
    int excl = incl - local;
    if (base + 0 < N_NODES) starts[base + 0] = excl;
    if (base + 1 < N_NODES) starts[base + 1] = excl + v0;
    if (base + 2 < N_NODES) starts[base + 2] = excl + v0 + v1;
    if (base + 3 < N_NODES) starts[base + 3] = excl + v0 + v1 + v2;
    if (t == 255) blockSums[b] = incl;
}

__global__ __launch_bounds__(128) void scan2_kernel(int* __restrict__ blockSums)
{
    __shared__ int s[128];
    int t = threadIdx.x;
    int v = (t < SCAN_NB) ? blockSums[t] : 0;
    s[t] = v;
    __syncthreads();
    for (int off = 1; off < 128; off <<= 1) {
        int x = (t >= off) ? s[t - off] : 0;
        __syncthreads();
        s[t] += x;
        __syncthreads();
    }
    if (t < SCAN_NB) blockSums[t] = s[t] - v;   // exclusive
}

__global__ __launch_bounds__(256) void scan3_kernel(
    int* __restrict__ starts, const int* __restrict__ blockSums,
    int* __restrict__ cursor)
{
    int i = blockIdx.x * 256 + threadIdx.x;
    if (i < N_NODES) {
        int v = starts[i] + blockSums[i >> 10];
        starts[i] = v;
        cursor[i] = v;
    }
}

__global__ __launch_bounds__(256) void scatter_kernel(
    const int* __restrict__ rows, const int* __restrict__ cols,
    int* __restrict__ cursor, int* __restrict__ csrCols)
{
    int e = blockIdx.x * 256 + threadIdx.x;
    if (e >= E_EDGES) return;
    int pos = atomicAdd(&cursor[rows[e]], 1);
    csrCols[pos] = cols[e];
}

// ---------------------------------------------------------------------------
// Kernel B: fused attention + aggregation.
// 32 threads/node, 4 dims/thread (uint4 KV load = 16B/lane).
// ---------------------------------------------------------------------------
__global__ __launch_bounds__(256) void att_agg_kernel(
    const float* __restrict__ Q, const unsigned* __restrict__ KV,
    const float* __restrict__ filt,
    const int* __restrict__ starts, const int* __restrict__ counts,
    const int* __restrict__ csrCols,
    float* __restrict__ out)
{
    int t = threadIdx.x;
    int node = blockIdx.x * 8 + (t >> 5);
    if (node >= N_NODES) return;
    int lane = t & 31;           // lane within node group
    int h = lane >> 3;           // head = (lane*4)>>5

    float4 q = ((const float4*)(Q + (size_t)node * 128))[lane];
    int s   = starts[node];
    int cnt = counts[node];

    float norm = 0.f;
    float ax = 0.f, ay = 0.f, az = 0.f, aw = 0.f;

    int i = 0;
    for (; i + 2 <= cnt; i += 2) {
        int c0 = csrCols[s + i];
        int c1 = csrCols[s + i + 1];
        uint4 kv0 = ((const uint4*)KV)[(size_t)c0 * 32 + lane];
        uint4 kv1 = ((const uint4*)KV)[(size_t)c1 * 32 + lane];
        float f0 = filt[c0 * HEAD + h];
        float f1 = filt[c1 * HEAD + h];

        float k0x = __uint_as_float(kv0.x << 16), v0x = __uint_as_float(kv0.x & 0xffff0000u);
        float k0y = __uint_as_float(kv0.y << 16), v0y = __uint_as_float(kv0.y & 0xffff0000u);
        float k0z = __uint_as_float(kv0.z << 16), v0z = __uint_as_float(kv0.z & 0xffff0000u);
        float k0w = __uint_as_float(kv0.w << 16), v0w = __uint_as_float(kv0.w & 0xffff0000u);
        float k1x = __uint_as_float(kv1.x << 16), v1x = __uint_as_float(kv1.x & 0xffff0000u);
        float k1y = __uint_as_float(kv1.y << 16), v1y = __uint_as_float(kv1.y & 0xffff0000u);
        float k1z = __uint_as_float(kv1.z << 16), v1z = __uint_as_float(kv1.z & 0xffff0000u);
        float k1w = __uint_as_float(kv1.w << 16), v1w = __uint_as_float(kv1.w & 0xffff0000u);

        float p0 = q.x * k0x + q.y * k0y + q.z * k0z + q.w * k0w;
        float p1 = q.x * k1x + q.y * k1y + q.z * k1z + q.w * k1w;
        p0 += __shfl_xor(p0, 1);   p1 += __shfl_xor(p1, 1);
        p0 += __shfl_xor(p0, 2);   p1 += __shfl_xor(p1, 2);
        p0 += __shfl_xor(p0, 4);   p1 += __shfl_xor(p1, 4);

        float w0 = __expf(fminf(fmaxf(p0, -10.f), 10.f) + f0);
        float w1 = __expf(fminf(fmaxf(p1, -10.f), 10.f) + f1);
        norm += w0 + w1;
        ax += w0 * v0x + w1 * v1x;
        ay += w0 * v0y + w1 * v1y;
        az += w0 * v0z + w1 * v1z;
        aw += w0 * v0w + w1 * v1w;
    }
    if (i < cnt) {
        int c0 = csrCols[s + i];
        uint4 kv0 = ((const uint4*)KV)[(size_t)c0 * 32 + lane];
        float f0 = filt[c0 * HEAD + h];
        float k0x = __uint_as_float(kv0.x << 16), v0x = __uint_as_float(kv0.x & 0xffff0000u);
        float k0y = __uint_as_float(kv0.y << 16), v0y = __uint_as_float(kv0.y & 0xffff0000u);
        float k0z = __uint_as_float(kv0.z << 16), v0z = __uint_as_float(kv0.z & 0xffff0000u);
        float k0w = __uint_as_float(kv0.w << 16), v0w = __uint_as_float(kv0.w & 0xffff0000u);
        float p0 = q.x * k0x + q.y * k0y + q.z * k0z + q.w * k0w;
        p0 += __shfl_xor(p0, 1);
        p0 += __shfl_xor(p0, 2);
        p0 += __shfl_xor(p0, 4);
        float w0 = __expf(fminf(fmaxf(p0, -10.f), 10.f) + f0);
        norm += w0;
        ax += w0 * v0x; ay += w0 * v0y; az += w0 * v0z; aw += w0 * v0w;
    }
    float inv = 1.0f / (norm + 1e-8f);
    ((float4*)(out + (size_t)node * 128))[lane] =
        make_float4(ax * inv, ay * inv, az * inv, aw * inv);
}

// ---------------------------------------------------------------------------
extern "C" void kernel_launch(void* const* d_in, const int* in_sizes, int n_in,
                              void* d_out, int out_size, void* d_ws, size_t ws_size,
                              hipStream_t stream) {
    const float* embeds = (const float*)d_in[0];
    const float* qT     = (const float*)d_in[1];
    const float* kT     = (const float*)d_in[2];
    const float* vT     = (const float*)d_in[3];
    const float* filt   = (const float*)d_in[4];
    const int*   rows   = (const int*)d_in[5];
    const int*   cols   = (const int*)d_in[6];
    float*       out    = (float*)d_out;

    // Workspace: Q: N*128 f32 | KV: N*128 u32 | counts,starts,cursor: N i32 |
    //            blockSums: 128 i32 | csrCols: E i32
    float*    Q  = (float*)d_ws;
    unsigned* KV = (unsigned*)(Q + (size_t)N_NODES * 128);
    int* counts    = (int*)(KV + (size_t)N_NODES * 128);
    int* starts    = counts + N_NODES;
    int* cursor    = starts + N_NODES;
    int* blockSums = cursor + N_NODES;
    int* csrCols   = blockSums + 128;

    // Split-bf16 weight planes ALIAS the csrCols region (192 KiB of 2.34 MiB).
    // Stream-ordered safe: wprep+qkv complete before scatter writes csrCols.
    unsigned short* WThi = (unsigned short*)csrCols;          // 96 KiB
    unsigned short* WTlo = WThi + 3 * 128 * 128;              // 96 KiB

    hipMemsetAsync(counts, 0, sizeof(int) * N_NODES, stream);

    wprep_kernel<<<12, 256, 0, stream>>>(qT, kT, vT, WThi, WTlo);
    qkv_mfma_kernel<<<(N_NODES + 63) / 64, 256, 0, stream>>>(embeds, WThi, WTlo, Q, KV);

    hist_kernel<<<(E_EDGES + 255) / 256, 256, 0, stream>>>(rows, counts);
    scan1_kernel<<<SCAN_NB, 256, 0, stream>>>(counts, starts, blockSums);
    scan2_kernel<<<1, 128, 0, stream>>>(blockSums);
    scan3_kernel<<<(N_NODES + 255) / 256, 256, 0, stream>>>(starts, blockSums, cursor);
    scatter_kernel<<<(E_EDGES + 255) / 256, 256, 0, stream>>>(rows, cols, cursor, csrCols);

    att_agg_kernel<<<(N_NODES + 7) / 8, 256, 0, stream>>>(
        Q, KV, filt, starts, counts, csrCols, out);
}

// Round 4
// 295.203 us; speedup vs baseline: 1.1616x; 1.1616x over previous
//
#include <hip/hip_runtime.h>

#define N_NODES 100000
#define E_EDGES 600000
#define LATDIM 128
#define HEAD 4
#define HDIM 32

#define SCAN_CHUNK 1024
#define SCAN_NB ((N_NODES + SCAN_CHUNK - 1) / SCAN_CHUNK)   // 98

typedef __bf16 bf16x8 __attribute__((ext_vector_type(8)));
typedef float  f32x4  __attribute__((ext_vector_type(4)));

__device__ __forceinline__ unsigned f32_to_bf16_rne(float x) {
    unsigned u = __float_as_uint(x);
    u += 0x7fffu + ((u >> 16) & 1u);   // round to nearest even
    return u >> 16;
}

__device__ __forceinline__ void bf16_split(float x, unsigned& hi, unsigned& lo) {
    unsigned hb = f32_to_bf16_rne(x);
    float hf = __uint_as_float(hb << 16);
    unsigned lb = f32_to_bf16_rne(x - hf);
    hi = hb; lo = lb;
}

// ---------------------------------------------------------------------------
// Weight prep: W[k][c] f32 -> WT_hi/WT_lo[m][c][k] bf16 (split precision).
// ---------------------------------------------------------------------------
__global__ __launch_bounds__(256) void wprep_kernel(
    const float* __restrict__ qT, const float* __restrict__ kT,
    const float* __restrict__ vT,
    unsigned short* __restrict__ WThi, unsigned short* __restrict__ WTlo)
{
    int g = blockIdx.x * 256 + threadIdx.x;      // 0..3071
    if (g >= 3072) return;
    int m    = g >> 10;          // 0..2
    int rem  = g & 1023;
    int c    = rem >> 3;         // 0..127
    int k0   = (rem & 7) * 16;   // 0..112
    const float* W = (m == 0) ? qT : (m == 1) ? kT : vT;

    unsigned short hi[16], lo[16];
    #pragma unroll
    for (int j = 0; j < 16; ++j) {
        float x = W[(size_t)(k0 + j) * 128 + c];
        unsigned hb, lb;
        bf16_split(x, hb, lb);
        hi[j] = (unsigned short)hb;
        lo[j] = (unsigned short)lb;
    }
    size_t off = (size_t)m * 16384 + (size_t)c * 128 + k0;
    *(uint4*)(WThi + off)     = *(const uint4*)&hi[0];
    *(uint4*)(WThi + off + 8) = *(const uint4*)&hi[8];
    *(uint4*)(WTlo + off)     = *(const uint4*)&lo[0];
    *(uint4*)(WTlo + off + 8) = *(const uint4*)&lo[8];
}

// ---------------------------------------------------------------------------
// Kernel A (MFMA): fused per-node Q/K/V transform via 16x16x32 bf16 MFMA with
// split-precision (hi+lo) operands: a*b ~= ah*bh + al*bh + ah*bl  (fp32-level).
// v4: T14 pipeline with NAMED SCALAR prefetch regs (rule #20: arrays across
// phase boundaries get promoted to LDS/scratch — r3 regression). Panels are
// fully straight-line. B overlays A's LDS (A is dead after frag hoist):
// 32 KiB total LDS + __launch_bounds__(256,4) -> 4 blocks/CU (was 2).
// ---------------------------------------------------------------------------
__global__ __launch_bounds__(256, 4) void qkv_mfma_kernel(
    const float* __restrict__ embeds,
    const unsigned short* __restrict__ WThi,
    const unsigned short* __restrict__ WTlo,
    float* __restrict__ Q, unsigned* __restrict__ KV)
{
    __shared__ __align__(16) char smem[32768];
    char* Ahi = smem;              // 16 KiB: 64 rows x 256B   (phase 1)
    char* Alo = smem + 16384;
    char* Bhi = smem;              // 16 KiB: 64 cols x 256B   (phase 2+, overlays A)
    char* Blo = smem + 16384;

    const int tid = threadIdx.x;
    const int rowBase = blockIdx.x * 64;

    uint4 pbh0, pbh1, pbh2, pbh3;      // named scalars: cannot be promoted
    uint4 pbl0, pbl1, pbl2, pbl3;

#define PF(MN, HN) do {                                                          \
        const char* _sh = (const char*)(WThi + (size_t)(MN) * 16384 + (size_t)(HN) * 8192); \
        const char* _sl = (const char*)(WTlo + (size_t)(MN) * 16384 + (size_t)(HN) * 8192); \
        pbh0 = *(const uint4*)(_sh + (size_t)(0 * 256 + tid) * 16);              \
        pbh1 = *(const uint4*)(_sh + (size_t)(1 * 256 + tid) * 16);              \
        pbh2 = *(const uint4*)(_sh + (size_t)(2 * 256 + tid) * 16);              \
        pbh3 = *(const uint4*)(_sh + (size_t)(3 * 256 + tid) * 16);              \
        pbl0 = *(const uint4*)(_sl + (size_t)(0 * 256 + tid) * 16);              \
        pbl1 = *(const uint4*)(_sl + (size_t)(1 * 256 + tid) * 16);              \
        pbl2 = *(const uint4*)(_sl + (size_t)(2 * 256 + tid) * 16);              \
        pbl3 = *(const uint4*)(_sl + (size_t)(3 * 256 + tid) * 16);              \
    } while (0)

#define COMMIT() do {                                                            \
        { int _i = 0 * 256 + tid; int _c = _i >> 4;                              \
          int _s = (_c * 256 + (_i & 15) * 16) ^ ((_c & 7) << 4);                \
          *(uint4*)(Bhi + _s) = pbh0; *(uint4*)(Blo + _s) = pbl0; }              \
        { int _i = 1 * 256 + tid; int _c = _i >> 4;                              \
          int _s = (_c * 256 + (_i & 15) * 16) ^ ((_c & 7) << 4);                \
          *(uint4*)(Bhi + _s) = pbh1; *(uint4*)(Blo + _s) = pbl1; }              \
        { int _i = 2 * 256 + tid; int _c = _i >> 4;                              \
          int _s = (_c * 256 + (_i & 15) * 16) ^ ((_c & 7) << 4);                \
          *(uint4*)(Bhi + _s) = pbh2; *(uint4*)(Blo + _s) = pbl2; }              \
        { int _i = 3 * 256 + tid; int _c = _i >> 4;                              \
          int _s = (_c * 256 + (_i & 15) * 16) ^ ((_c & 7) << 4);                \
          *(uint4*)(Bhi + _s) = pbh3; *(uint4*)(Blo + _s) = pbl3; }              \
    } while (0)

#define MFMA_PANEL(ACC) do {                                                     \
        _Pragma("unroll")                                                        \
        for (int kk = 0; kk < 4; ++kk) {                                         \
            _Pragma("unroll")                                                    \
            for (int n = 0; n < 4; ++n) {                                        \
                int brow = n * 16 + lrow;                                        \
                int byte = brow * 256 + kk * 64 + kg * 16;                       \
                int swz  = byte ^ ((lrow & 7) << 4);                             \
                bf16x8 bh = __builtin_bit_cast(bf16x8, *(const uint4*)(Bhi + swz)); \
                bf16x8 bl = __builtin_bit_cast(bf16x8, *(const uint4*)(Blo + swz)); \
                ACC[n] = __builtin_amdgcn_mfma_f32_16x16x32_bf16(a_hi[kk], bh, ACC[n], 0, 0, 0); \
                ACC[n] = __builtin_amdgcn_mfma_f32_16x16x32_bf16(a_lo[kk], bh, ACC[n], 0, 0, 0); \
                ACC[n] = __builtin_amdgcn_mfma_f32_16x16x32_bf16(a_hi[kk], bl, ACC[n], 0, 0, 0); \
            }                                                                    \
        }                                                                        \
    } while (0)

#define ZACC(ACC) f32x4 ACC[4] = { {0.f,0.f,0.f,0.f}, {0.f,0.f,0.f,0.f},         \
                                   {0.f,0.f,0.f,0.f}, {0.f,0.f,0.f,0.f} }

#define STORE_Q(ACC, H) do {                                                     \
        _Pragma("unroll")                                                        \
        for (int n = 0; n < 4; ++n)                                              \
        _Pragma("unroll")                                                        \
        for (int j = 0; j < 4; ++j) {                                            \
            int gr  = rowBase + wv * 16 + orow + j;                              \
            int col = (H) * 64 + n * 16 + lrow;                                  \
            if (gr < N_NODES) Q[(size_t)gr * 128 + col] = ACC[n][j];             \
        }                                                                        \
    } while (0)

#define STORE_KV(ACC, H) do {                                                    \
        _Pragma("unroll")                                                        \
        for (int n = 0; n < 4; ++n)                                              \
        _Pragma("unroll")                                                        \
        for (int j = 0; j < 4; ++j) {                                            \
            int gr  = rowBase + wv * 16 + orow + j;                              \
            int col = (H) * 64 + n * 16 + lrow;                                  \
            if (gr < N_NODES) {                                                  \
                unsigned pk = f32_to_bf16_rne(kreg[n][j])                        \
                            | (f32_to_bf16_rne(ACC[n][j]) << 16);                \
                KV[(size_t)gr * 128 + col] = pk;                                 \
            }                                                                    \
        }                                                                        \
    } while (0)

    // ---- prefetch B(panel 0 = m0,h0): overlaps the whole A-stage ----
    PF(0, 0);

    // ---- stage A: load embeds f32, split to bf16 hi/lo, swizzled LDS ----
    #pragma unroll
    for (int it = 0; it < 8; ++it) {
        int idx = it * 256 + tid;          // 0..2047 float4 chunks
        int r  = idx >> 5;                 // 0..63
        int c4 = idx & 31;                 // 0..31
        int gr = rowBase + r;
        float4 v = make_float4(0.f, 0.f, 0.f, 0.f);
        if (gr < N_NODES) v = ((const float4*)embeds)[(size_t)gr * 32 + c4];
        unsigned hx, lx, hy, ly, hz, lz, hw, lw;
        bf16_split(v.x, hx, lx); bf16_split(v.y, hy, ly);
        bf16_split(v.z, hz, lz); bf16_split(v.w, hw, lw);
        uint2 hp = make_uint2(hx | (hy << 16), hz | (hw << 16));
        uint2 lp = make_uint2(lx | (ly << 16), lz | (lw << 16));
        int byte = r * 256 + c4 * 8;
        int swz  = byte ^ ((r & 7) << 4);
        *(uint2*)(Ahi + swz) = hp;
        *(uint2*)(Alo + swz) = lp;
    }
    __syncthreads();

    const int lane = tid & 63;
    const int wv   = tid >> 6;         // 0..3 (wave -> 16-row tile)
    const int lrow = lane & 15;
    const int kg   = lane >> 4;        // 0..3 (k-group of MFMA operand)
    const int arow = wv * 16 + lrow;   // 0..63
    const int orow = kg << 2;          // C/D row base within 16-row tile

    // ---- hoist A fragments (one-time; A LDS is dead afterwards) ----
    bf16x8 a_hi[4], a_lo[4];
    #pragma unroll
    for (int kk = 0; kk < 4; ++kk) {
        int byte = arow * 256 + kk * 64 + kg * 16;
        int swz  = byte ^ ((lrow & 7) << 4);     // (arow&7)==(lrow&7)
        a_hi[kk] = __builtin_bit_cast(bf16x8, *(const uint4*)(Ahi + swz));
        a_lo[kk] = __builtin_bit_cast(bf16x8, *(const uint4*)(Alo + swz));
    }
    __syncthreads();           // all waves done reading A -> B may overlay

    COMMIT();                  // B(m0,h0) into LDS (loads have long landed)
    __syncthreads();

    f32x4 kreg[4];

    // ---- panel (m0,h0): Q, h=0 ----
    {
        PF(1, 0);
        ZACC(acc);
        MFMA_PANEL(acc);
        STORE_Q(acc, 0);
        __syncthreads(); COMMIT(); __syncthreads();
    }
    // ---- panel (m1,h0): K kept in regs ----
    {
        PF(2, 0);
        ZACC(acc);
        MFMA_PANEL(acc);
        kreg[0] = acc[0]; kreg[1] = acc[1]; kreg[2] = acc[2]; kreg[3] = acc[3];
        __syncthreads(); COMMIT(); __syncthreads();
    }
    // ---- panel (m2,h0): V -> pack KV, h=0 ----
    {
        PF(0, 1);
        ZACC(acc);
        MFMA_PANEL(acc);
        STORE_KV(acc, 0);
        __syncthreads(); COMMIT(); __syncthreads();
    }
    // ---- panel (m0,h1): Q, h=1 ----
    {
        PF(1, 1);
        ZACC(acc);
        MFMA_PANEL(acc);
        STORE_Q(acc, 1);
        __syncthreads(); COMMIT(); __syncthreads();
    }
    // ---- panel (m1,h1): K kept in regs ----
    {
        PF(2, 1);
        ZACC(acc);
        MFMA_PANEL(acc);
        kreg[0] = acc[0]; kreg[1] = acc[1]; kreg[2] = acc[2]; kreg[3] = acc[3];
        __syncthreads(); COMMIT(); __syncthreads();
    }
    // ---- panel (m2,h1): V -> pack KV, h=1 (no prefetch) ----
    {
        ZACC(acc);
        MFMA_PANEL(acc);
        STORE_KV(acc, 1);
    }

#undef PF
#undef COMMIT
#undef MFMA_PANEL
#undef ZACC
#undef STORE_Q
#undef STORE_KV
}

// ---------------------------------------------------------------------------
// CSR build: histogram -> exclusive scan -> scatter (stores COLS directly)
// ---------------------------------------------------------------------------
__global__ __launch_bounds__(256) void hist_kernel(
    const int* __restrict__ rows, int* __restrict__ counts)
{
    int e = blockIdx.x * 256 + threadIdx.x;
    if (e < E_EDGES) atomicAdd(&counts[rows[e]], 1);
}

__global__ __launch_bounds__(256) void scan1_kernel(
    const int* __restrict__ counts, int* __restrict__ starts,
    int* __restrict__ blockSums)
{
    __shared__ int s[256];
    int b = blockIdx.x, t = threadIdx.x;
    int base = b * SCAN_CHUNK + t * 4;
    int v0 = (base + 0 < N_NODES) ? counts[base + 0] : 0;
    int v1 = (base + 1 < N_NODES) ? counts[base + 1] : 0;
    int v2 = (base + 2 < N_NODES) ? counts[base + 2] : 0;
    int v3 = (base + 3 < N_NODES) ? counts[base + 3] : 0;
    int local = v0 + v1 + v2 + v3;
    s[t] = local;
    __syncthreads();
    for (int off = 1; off < 256; off <<= 1) {
        int x = (t >= off) ? s[t - off] : 0;
        __syncthreads();
        s[t] += x;
        __syncthreads();
    }
    int incl = s[t];
    int excl = incl - local;
    if (base + 0 < N_NODES) starts[base + 0] = excl;
    if (base + 1 < N_NODES) starts[base + 1] = excl + v0;
    if (base + 2 < N_NODES) starts[base + 2] = excl + v0 + v1;
    if (base + 3 < N_NODES) starts[base + 3] = excl + v0 + v1 + v2;
    if (t == 255) blockSums[b] = incl;
}

__global__ __launch_bounds__(128) void scan2_kernel(int* __restrict__ blockSums)
{
    __shared__ int s[128];
    int t = threadIdx.x;
    int v = (t < SCAN_NB) ? blockSums[t] : 0;
    s[t] = v;
    __syncthreads();
    for (int off = 1; off < 128; off <<= 1) {
        int x = (t >= off) ? s[t - off] : 0;
        __syncthreads();
        s[t] += x;
        __syncthreads();
    }
    if (t < SCAN_NB) blockSums[t] = s[t] - v;   // exclusive
}

__global__ __launch_bounds__(256) void scan3_kernel(
    int* __restrict__ starts, const int* __restrict__ blockSums,
    int* __restrict__ cursor)
{
    int i = blockIdx.x * 256 + threadIdx.x;
    if (i < N_NODES) {
        int v = starts[i] + blockSums[i >> 10];
        starts[i] = v;
        cursor[i] = v;
    }
}

__global__ __launch_bounds__(256) void scatter_kernel(
    const int* __restrict__ rows, const int* __restrict__ cols,
    int* __restrict__ cursor, int* __restrict__ csrCols)
{
    int e = blockIdx.x * 256 + threadIdx.x;
    if (e >= E_EDGES) return;
    int pos = atomicAdd(&cursor[rows[e]], 1);
    csrCols[pos] = cols[e];
}

// ---------------------------------------------------------------------------
// Kernel B: fused attention + aggregation.
// 32 threads/node, 4 dims/thread (uint4 KV load = 16B/lane).
// ---------------------------------------------------------------------------
__global__ __launch_bounds__(256) void att_agg_kernel(
    const float* __restrict__ Q, const unsigned* __restrict__ KV,
    const float* __restrict__ filt,
    const int* __restrict__ starts, const int* __restrict__ counts,
    const int* __restrict__ csrCols,
    float* __restrict__ out)
{
    int t = threadIdx.x;
    int node = blockIdx.x * 8 + (t >> 5);
    if (node >= N_NODES) return;
    int lane = t & 31;           // lane within node group
    int h = lane >> 3;           // head = (lane*4)>>5

    float4 q = ((const float4*)(Q + (size_t)node * 128))[lane];
    int s   = starts[node];
    int cnt = counts[node];

    float norm = 0.f;
    float ax = 0.f, ay = 0.f, az = 0.f, aw = 0.f;

    int i = 0;
    for (; i + 2 <= cnt; i += 2) {
        int c0 = csrCols[s + i];
        int c1 = csrCols[s + i + 1];
        uint4 kv0 = ((const uint4*)KV)[(size_t)c0 * 32 + lane];
        uint4 kv1 = ((const uint4*)KV)[(size_t)c1 * 32 + lane];
        float f0 = filt[c0 * HEAD + h];
        float f1 = filt[c1 * HEAD + h];

        float k0x = __uint_as_float(kv0.x << 16), v0x = __uint_as_float(kv0.x & 0xffff0000u);
        float k0y = __uint_as_float(kv0.y << 16), v0y = __uint_as_float(kv0.y & 0xffff0000u);
        float k0z = __uint_as_float(kv0.z << 16), v0z = __uint_as_float(kv0.z & 0xffff0000u);
        float k0w = __uint_as_float(kv0.w << 16), v0w = __uint_as_float(kv0.w & 0xffff0000u);
        float k1x = __uint_as_float(kv1.x << 16), v1x = __uint_as_float(kv1.x & 0xffff0000u);
        float k1y = __uint_as_float(kv1.y << 16), v1y = __uint_as_float(kv1.y & 0xffff0000u);
        float k1z = __uint_as_float(kv1.z << 16), v1z = __uint_as_float(kv1.z & 0xffff0000u);
        float k1w = __uint_as_float(kv1.w << 16), v1w = __uint_as_float(kv1.w & 0xffff0000u);

        float p0 = q.x * k0x + q.y * k0y + q.z * k0z + q.w * k0w;
        float p1 = q.x * k1x + q.y * k1y + q.z * k1z + q.w * k1w;
        p0 += __shfl_xor(p0, 1);   p1 += __shfl_xor(p1, 1);
        p0 += __shfl_xor(p0, 2);   p1 += __shfl_xor(p1, 2);
        p0 += __shfl_xor(p0, 4);   p1 += __shfl_xor(p1, 4);

        float w0 = __expf(fminf(fmaxf(p0, -10.f), 10.f) + f0);
        float w1 = __expf(fminf(fmaxf(p1, -10.f), 10.f) + f1);
        norm += w0 + w1;
        ax += w0 * v0x + w1 * v1x;
        ay += w0 * v0y + w1 * v1y;
        az += w0 * v0z + w1 * v1z;
        aw += w0 * v0w + w1 * v1w;
    }
    if (i < cnt) {
        int c0 = csrCols[s + i];
        uint4 kv0 = ((const uint4*)KV)[(size_t)c0 * 32 + lane];
        float f0 = filt[c0 * HEAD + h];
        float k0x = __uint_as_float(kv0.x << 16), v0x = __uint_as_float(kv0.x & 0xffff0000u);
        float k0y = __uint_as_float(kv0.y << 16), v0y = __uint_as_float(kv0.y & 0xffff0000u);
        float k0z = __uint_as_float(kv0.z << 16), v0z = __uint_as_float(kv0.z & 0xffff0000u);
        float k0w = __uint_as_float(kv0.w << 16), v0w = __uint_as_float(kv0.w & 0xffff0000u);
        float p0 = q.x * k0x + q.y * k0y + q.z * k0z + q.w * k0w;
        p0 += __shfl_xor(p0, 1);
        p0 += __shfl_xor(p0, 2);
        p0 += __shfl_xor(p0, 4);
        float w0 = __expf(fminf(fmaxf(p0, -10.f), 10.f) + f0);
        norm += w0;
        ax += w0 * v0x; ay += w0 * v0y; az += w0 * v0z; aw += w0 * v0w;
    }
    float inv = 1.0f / (norm + 1e-8f);
    ((float4*)(out + (size_t)node * 128))[lane] =
        make_float4(ax * inv, ay * inv, az * inv, aw * inv);
}

// ---------------------------------------------------------------------------
extern "C" void kernel_launch(void* const* d_in, const int* in_sizes, int n_in,
                              void* d_out, int out_size, void* d_ws, size_t ws_size,
                              hipStream_t stream) {
    const float* embeds = (const float*)d_in[0];
    const float* qT     = (const float*)d_in[1];
    const float* kT     = (const float*)d_in[2];
    const float* vT     = (const float*)d_in[3];
    const float* filt   = (const float*)d_in[4];
    const int*   rows   = (const int*)d_in[5];
    const int*   cols   = (const int*)d_in[6];
    float*       out    = (float*)d_out;

    // Workspace: Q: N*128 f32 | KV: N*128 u32 | counts,starts,cursor: N i32 |
    //            blockSums: 128 i32 | csrCols: E i32
    float*    Q  = (float*)d_ws;
    unsigned* KV = (unsigned*)(Q + (size_t)N_NODES * 128);
    int* counts    = (int*)(KV + (size_t)N_NODES * 128);
    int* starts    = counts + N_NODES;
    int* cursor    = starts + N_NODES;
    int* blockSums = cursor + N_NODES;
    int* csrCols   = blockSums + 128;

    // Split-bf16 weight planes ALIAS the csrCols region (192 KiB of 2.34 MiB).
    // Stream-ordered safe: wprep+qkv complete before scatter writes csrCols.
    unsigned short* WThi = (unsigned short*)csrCols;          // 96 KiB
    unsigned short* WTlo = WThi + 3 * 128 * 128;              // 96 KiB

    hipMemsetAsync(counts, 0, sizeof(int) * N_NODES, stream);

    wprep_kernel<<<12, 256, 0, stream>>>(qT, kT, vT, WThi, WTlo);
    qkv_mfma_kernel<<<(N_NODES + 63) / 64, 256, 0, stream>>>(embeds, WThi, WTlo, Q, KV);

    hist_kernel<<<(E_EDGES + 255) / 256, 256, 0, stream>>>(rows, counts);
    scan1_kernel<<<SCAN_NB, 256, 0, stream>>>(counts, starts, blockSums);
    scan2_kernel<<<1, 128, 0, stream>>>(blockSums);
    scan3_kernel<<<(N_NODES + 255) / 256, 256, 0, stream>>>(starts, blockSums, cursor);
    scatter_kernel<<<(E_EDGES + 255) / 256, 256, 0, stream>>>(rows, cols, cursor, csrCols);

    att_agg_kernel<<<(N_NODES + 7) / 8, 256, 0, stream>>>(
        Q, KV, filt, starts, counts, csrCols, out);
}

// Round 5
// 272.437 us; speedup vs baseline: 1.2587x; 1.0836x over previous
//
#include <hip/hip_runtime.h>

#define N_NODES 100000
#define E_EDGES 600000
#define LATDIM 128
#define HEAD 4
#define HDIM 32

#define SCAN_NB 98          // 98 blocks x 1024 elems >= N_NODES

typedef __bf16 bf16x8 __attribute__((ext_vector_type(8)));
typedef float  f32x4  __attribute__((ext_vector_type(4)));

__device__ __forceinline__ unsigned f32_to_bf16_rne(float x) {
    unsigned u = __float_as_uint(x);
    u += 0x7fffu + ((u >> 16) & 1u);   // round to nearest even
    return u >> 16;
}

__device__ __forceinline__ void bf16_split(float x, unsigned& hi, unsigned& lo) {
    unsigned hb = f32_to_bf16_rne(x);
    float hf = __uint_as_float(hb << 16);
    unsigned lb = f32_to_bf16_rne(x - hf);
    hi = hb; lo = lb;
}

// ---------------------------------------------------------------------------
// Weight prep + workspace zeroing (folds the memset + scan-state init).
// W[k][c] f32 -> WT_hi/WT_lo[m][c][k] bf16 (split precision).
// ---------------------------------------------------------------------------
__global__ __launch_bounds__(256) void wprep_kernel(
    const float* __restrict__ qT, const float* __restrict__ kT,
    const float* __restrict__ vT,
    unsigned short* __restrict__ WThi, unsigned short* __restrict__ WTlo,
    int* __restrict__ counts, unsigned* __restrict__ state)
{
    int g = blockIdx.x * 256 + threadIdx.x;      // 0..25087

    // zero counts (graph replays => must re-zero every launch)
    for (int i = g; i < N_NODES; i += SCAN_NB * 256) counts[i] = 0;
    if (g < 128) state[g] = 0u;

    if (g >= 3072) return;
    int m    = g >> 10;          // 0..2
    int rem  = g & 1023;
    int c    = rem >> 3;         // 0..127
    int k0   = (rem & 7) * 16;   // 0..112
    const float* W = (m == 0) ? qT : (m == 1) ? kT : vT;

    unsigned short hi[16], lo[16];
    #pragma unroll
    for (int j = 0; j < 16; ++j) {
        float x = W[(size_t)(k0 + j) * 128 + c];
        unsigned hb, lb;
        bf16_split(x, hb, lb);
        hi[j] = (unsigned short)hb;
        lo[j] = (unsigned short)lb;
    }
    size_t off = (size_t)m * 16384 + (size_t)c * 128 + k0;
    *(uint4*)(WThi + off)     = *(const uint4*)&hi[0];
    *(uint4*)(WThi + off + 8) = *(const uint4*)&hi[8];
    *(uint4*)(WTlo + off)     = *(const uint4*)&lo[0];
    *(uint4*)(WTlo + off + 8) = *(const uint4*)&lo[8];
}

// ---------------------------------------------------------------------------
// Kernel A (MFMA): fused per-node Q/K/V transform, split-precision bf16
// (ah*bh + al*bh + ah*bl ~ fp32). v5:
//  - 512 thr / 128 nodes per block (8 waves x 16 rows) -> 782 blocks
//  - B DOUBLE-buffered in the LDS freed by A (B0 overlays Ahi, B1 Alo);
//    one barrier per panel instead of two (commit goes to the idle buffer)
//  - named scalar prefetch regs (rule #20), straight-line panels
//  - edge histogram fused as a grid-stride prologue (kills hist dispatch)
// LDS peak 64 KiB -> 2 blocks/CU; __launch_bounds__(512,2) so the RA
// doesn't squeeze VGPRs to 64 and spill (r4 regression).
// ---------------------------------------------------------------------------
__global__ __launch_bounds__(512, 2) void qkv_mfma_kernel(
    const float* __restrict__ embeds,
    const unsigned short* __restrict__ WThi,
    const unsigned short* __restrict__ WTlo,
    const int* __restrict__ rows,
    int* __restrict__ counts,
    float* __restrict__ Q, unsigned* __restrict__ KV)
{
    __shared__ __align__(16) char smem[65536];
    char* Ahi = smem;                // 32 KiB: 128 rows x 256B (phase 1)
    char* Alo = smem + 32768;        // 32 KiB
    char* B0h = smem;                // buf0 overlays Ahi (A dead after hoist)
    char* B0l = smem + 16384;
    char* B1h = smem + 32768;        // buf1 overlays Alo
    char* B1l = smem + 49152;

    const int tid = threadIdx.x;
    const int rowBase = blockIdx.x * 128;

    uint4 pbh0, pbh1, pbl0, pbl1;    // named scalars: cannot be promoted

#define PF(MN, HN) do {                                                          \
        const char* _sh = (const char*)(WThi + (size_t)(MN) * 16384 + (size_t)(HN) * 8192); \
        const char* _sl = (const char*)(WTlo + (size_t)(MN) * 16384 + (size_t)(HN) * 8192); \
        pbh0 = *(const uint4*)(_sh + (size_t)tid * 16);                          \
        pbh1 = *(const uint4*)(_sh + (size_t)(512 + tid) * 16);                  \
        pbl0 = *(const uint4*)(_sl + (size_t)tid * 16);                          \
        pbl1 = *(const uint4*)(_sl + (size_t)(512 + tid) * 16);                  \
    } while (0)

#define COMMIT(BHI, BLO) do {                                                    \
        { int _i = tid; int _c = _i >> 4;                                        \
          int _s = (_c * 256 + (_i & 15) * 16) ^ ((_c & 7) << 4);                \
          *(uint4*)((BHI) + _s) = pbh0; *(uint4*)((BLO) + _s) = pbl0; }          \
        { int _i = 512 + tid; int _c = _i >> 4;                                  \
          int _s = (_c * 256 + (_i & 15) * 16) ^ ((_c & 7) << 4);                \
          *(uint4*)((BHI) + _s) = pbh1; *(uint4*)((BLO) + _s) = pbl1; }          \
    } while (0)

#define MFMA_PANEL(ACC, BHI, BLO) do {                                           \
        _Pragma("unroll")                                                        \
        for (int kk = 0; kk < 4; ++kk) {                                         \
            _Pragma("unroll")                                                    \
            for (int n = 0; n < 4; ++n) {                                        \
                int brow = n * 16 + lrow;                                        \
                int byte = brow * 256 + kk * 64 + kg * 16;                       \
                int swz  = byte ^ ((lrow & 7) << 4);                             \
                bf16x8 bh = __builtin_bit_cast(bf16x8, *(const uint4*)((BHI) + swz)); \
                bf16x8 bl = __builtin_bit_cast(bf16x8, *(const uint4*)((BLO) + swz)); \
                ACC[n] = __builtin_amdgcn_mfma_f32_16x16x32_bf16(a_hi[kk], bh, ACC[n], 0, 0, 0); \
                ACC[n] = __builtin_amdgcn_mfma_f32_16x16x32_bf16(a_lo[kk], bh, ACC[n], 0, 0, 0); \
                ACC[n] = __builtin_amdgcn_mfma_f32_16x16x32_bf16(a_hi[kk], bl, ACC[n], 0, 0, 0); \
            }                                                                    \
        }                                                                        \
    } while (0)

#define ZACC(ACC) f32x4 ACC[4] = { {0.f,0.f,0.f,0.f}, {0.f,0.f,0.f,0.f},         \
                                   {0.f,0.f,0.f,0.f}, {0.f,0.f,0.f,0.f} }

#define STORE_Q(ACC, H) do {                                                     \
        _Pragma("unroll")                                                        \
        for (int n = 0; n < 4; ++n)                                              \
        _Pragma("unroll")                                                        \
        for (int j = 0; j < 4; ++j) {                                            \
            int gr  = rowBase + wv * 16 + orow + j;                              \
            int col = (H) * 64 + n * 16 + lrow;                                  \
            if (gr < N_NODES) Q[(size_t)gr * 128 + col] = ACC[n][j];             \
        }                                                                        \
    } while (0)

#define STORE_KV(ACC, H) do {                                                    \
        _Pragma("unroll")                                                        \
        for (int n = 0; n < 4; ++n)                                              \
        _Pragma("unroll")                                                        \
        for (int j = 0; j < 4; ++j) {                                            \
            int gr  = rowBase + wv * 16 + orow + j;                              \
            int col = (H) * 64 + n * 16 + lrow;                                  \
            if (gr < N_NODES) {                                                  \
                unsigned pk = f32_to_bf16_rne(kreg[n][j])                        \
                            | (f32_to_bf16_rne(ACC[n][j]) << 16);                \
                KV[(size_t)gr * 128 + col] = pk;                                 \
            }                                                                    \
        }                                                                        \
    } while (0)

    // ---- prefetch B(panel 0 = m0,h0): overlaps hist + A-stage ----
    PF(0, 0);

    // ---- fused edge histogram (fire-and-forget atomics) ----
    for (int e = blockIdx.x * 512 + tid; e < E_EDGES; e += gridDim.x * 512)
        atomicAdd(&counts[rows[e]], 1);

    // ---- stage A: load embeds f32, split to bf16 hi/lo, swizzled LDS ----
    #pragma unroll
    for (int it = 0; it < 8; ++it) {
        int idx = it * 512 + tid;          // 0..4095 float4 chunks
        int r  = idx >> 5;                 // 0..127
        int c4 = idx & 31;                 // 0..31
        int gr = rowBase + r;
        float4 v = make_float4(0.f, 0.f, 0.f, 0.f);
        if (gr < N_NODES) v = ((const float4*)embeds)[(size_t)gr * 32 + c4];
        unsigned hx, lx, hy, ly, hz, lz, hw, lw;
        bf16_split(v.x, hx, lx); bf16_split(v.y, hy, ly);
        bf16_split(v.z, hz, lz); bf16_split(v.w, hw, lw);
        uint2 hp = make_uint2(hx | (hy << 16), hz | (hw << 16));
        uint2 lp = make_uint2(lx | (ly << 16), lz | (lw << 16));
        int byte = r * 256 + c4 * 8;
        int swz  = byte ^ ((r & 7) << 4);
        *(uint2*)(Ahi + swz) = hp;
        *(uint2*)(Alo + swz) = lp;
    }
    __syncthreads();

    const int lane = tid & 63;
    const int wv   = tid >> 6;         // 0..7 (wave -> 16-row tile)
    const int lrow = lane & 15;
    const int kg   = lane >> 4;        // 0..3 (k-group of MFMA operand)
    const int arow = wv * 16 + lrow;   // 0..127
    const int orow = kg << 2;          // C/D row base within 16-row tile

    // ---- hoist A fragments (one-time; A LDS dead afterwards) ----
    bf16x8 a_hi[4], a_lo[4];
    #pragma unroll
    for (int kk = 0; kk < 4; ++kk) {
        int byte = arow * 256 + kk * 64 + kg * 16;
        int swz  = byte ^ ((lrow & 7) << 4);     // (arow&7)==(lrow&7)
        a_hi[kk] = __builtin_bit_cast(bf16x8, *(const uint4*)(Ahi + swz));
        a_lo[kk] = __builtin_bit_cast(bf16x8, *(const uint4*)(Alo + swz));
    }
    __syncthreads();           // all waves done reading A -> B may overlay

    COMMIT(B0h, B0l);          // B(m0,h0) -> buf0 (overlays Ahi)
    __syncthreads();

    f32x4 kreg[4];

    // ---- p0: Q h0 (read buf0), prefetch (m1,h0) -> buf1 ----
    {
        PF(1, 0); ZACC(acc);
        MFMA_PANEL(acc, B0h, B0l);
        STORE_Q(acc, 0);
        COMMIT(B1h, B1l); __syncthreads();
    }
    // ---- p1: K h0 (read buf1), prefetch (m2,h0) -> buf0 ----
    {
        PF(2, 0); ZACC(acc);
        MFMA_PANEL(acc, B1h, B1l);
        kreg[0] = acc[0]; kreg[1] = acc[1]; kreg[2] = acc[2]; kreg[3] = acc[3];
        COMMIT(B0h, B0l); __syncthreads();
    }
    // ---- p2: V h0 -> pack KV (read buf0), prefetch (m0,h1) -> buf1 ----
    {
        PF(0, 1); ZACC(acc);
        MFMA_PANEL(acc, B0h, B0l);
        STORE_KV(acc, 0);
        COMMIT(B1h, B1l); __syncthreads();
    }
    // ---- p3: Q h1 (read buf1), prefetch (m1,h1) -> buf0 ----
    {
        PF(1, 1); ZACC(acc);
        MFMA_PANEL(acc, B1h, B1l);
        STORE_Q(acc, 1);
        COMMIT(B0h, B0l); __syncthreads();
    }
    // ---- p4: K h1 (read buf0), prefetch (m2,h1) -> buf1 ----
    {
        PF(2, 1); ZACC(acc);
        MFMA_PANEL(acc, B0h, B0l);
        kreg[0] = acc[0]; kreg[1] = acc[1]; kreg[2] = acc[2]; kreg[3] = acc[3];
        COMMIT(B1h, B1l); __syncthreads();
    }
    // ---- p5: V h1 -> pack KV (read buf1), no prefetch ----
    {
        ZACC(acc);
        MFMA_PANEL(acc, B1h, B1l);
        STORE_KV(acc, 1);
    }

#undef PF
#undef COMMIT
#undef MFMA_PANEL
#undef ZACC
#undef STORE_Q
#undef STORE_KV
}

// ---------------------------------------------------------------------------
// Single-pass exclusive scan with decoupled lookback (replaces scan1/2/3).
// 98 blocks <= 256 CUs -> all co-resident; state word = (sum<<2)|st,
// st: 0=invalid 1=aggregate 2=inclusive-prefix. Device-scope atomics.
// ---------------------------------------------------------------------------
__global__ __launch_bounds__(256) void scan_lb_kernel(
    const int* __restrict__ counts, int* __restrict__ starts,
    int* __restrict__ cursor, unsigned* __restrict__ state)
{
    __shared__ int s[256];
    __shared__ int bcast;
    int b = blockIdx.x, t = threadIdx.x;
    int base = b * 1024 + t * 4;
    int v0 = (base + 0 < N_NODES) ? counts[base + 0] : 0;
    int v1 = (base + 1 < N_NODES) ? counts[base + 1] : 0;
    int v2 = (base + 2 < N_NODES) ? counts[base + 2] : 0;
    int v3 = (base + 3 < N_NODES) ? counts[base + 3] : 0;
    int local = v0 + v1 + v2 + v3;
    s[t] = local;
    __syncthreads();
    for (int off = 1; off < 256; off <<= 1) {
        int x = (t >= off) ? s[t - off] : 0;
        __syncthreads();
        s[t] += x;
        __syncthreads();
    }
    int incl  = s[t];
    int excl  = incl - local;
    int total = s[255];

    if (t == 0) {
        int sum = 0;
        if (b == 0) {
            atomicExch(&state[0], ((unsigned)total << 2) | 2u);
        } else {
            atomicExch(&state[b], ((unsigned)total << 2) | 1u);
            int i = b - 1;
            while (true) {
                unsigned w = atomicAdd(&state[i], 0u);   // atomic load
                unsigned st = w & 3u;
                if (st == 0u) continue;                  // spin: not published
                sum += (int)(w >> 2);
                if (st == 2u) break;                     // found a prefix
                --i;                                     // aggregate: keep walking
            }
            atomicExch(&state[b], ((unsigned)(sum + total) << 2) | 2u);
        }
        bcast = sum;
    }
    __syncthreads();
    int e = excl + bcast;
    if (base + 0 < N_NODES) { starts[base + 0] = e;                cursor[base + 0] = e; }
    if (base + 1 < N_NODES) { starts[base + 1] = e + v0;           cursor[base + 1] = e + v0; }
    if (base + 2 < N_NODES) { starts[base + 2] = e + v0 + v1;      cursor[base + 2] = e + v0 + v1; }
    if (base + 3 < N_NODES) { starts[base + 3] = e + v0 + v1 + v2; cursor[base + 3] = e + v0 + v1 + v2; }
}

__global__ __launch_bounds__(256) void scatter_kernel(
    const int* __restrict__ rows, const int* __restrict__ cols,
    int* __restrict__ cursor, int* __restrict__ csrCols)
{
    int e = blockIdx.x * 256 + threadIdx.x;
    if (e >= E_EDGES) return;
    int pos = atomicAdd(&cursor[rows[e]], 1);
    csrCols[pos] = cols[e];
}

// ---------------------------------------------------------------------------
// Kernel B: fused attention + aggregation.
// 32 threads/node, 4 dims/thread (uint4 KV load = 16B/lane).
// ---------------------------------------------------------------------------
__global__ __launch_bounds__(256) void att_agg_kernel(
    const float* __restrict__ Q, const unsigned* __restrict__ KV,
    const float* __restrict__ filt,
    const int* __restrict__ starts, const int* __restrict__ counts,
    const int* __restrict__ csrCols,
    float* __restrict__ out)
{
    int t = threadIdx.x;
    int node = blockIdx.x * 8 + (t >> 5);
    if (node >= N_NODES) return;
    int lane = t & 31;           // lane within node group
    int h = lane >> 3;           // head = (lane*4)>>5

    float4 q = ((const float4*)(Q + (size_t)node * 128))[lane];
    int s   = starts[node];
    int cnt = counts[node];

    float norm = 0.f;
    float ax = 0.f, ay = 0.f, az = 0.f, aw = 0.f;

    int i = 0;
    for (; i + 2 <= cnt; i += 2) {
        int c0 = csrCols[s + i];
        int c1 = csrCols[s + i + 1];
        uint4 kv0 = ((const uint4*)KV)[(size_t)c0 * 32 + lane];
        uint4 kv1 = ((const uint4*)KV)[(size_t)c1 * 32 + lane];
        float f0 = filt[c0 * HEAD + h];
        float f1 = filt[c1 * HEAD + h];

        float k0x = __uint_as_float(kv0.x << 16), v0x = __uint_as_float(kv0.x & 0xffff0000u);
        float k0y = __uint_as_float(kv0.y << 16), v0y = __uint_as_float(kv0.y & 0xffff0000u);
        float k0z = __uint_as_float(kv0.z << 16), v0z = __uint_as_float(kv0.z & 0xffff0000u);
        float k0w = __uint_as_float(kv0.w << 16), v0w = __uint_as_float(kv0.w & 0xffff0000u);
        float k1x = __uint_as_float(kv1.x << 16), v1x = __uint_as_float(kv1.x & 0xffff0000u);
        float k1y = __uint_as_float(kv1.y << 16), v1y = __uint_as_float(kv1.y & 0xffff0000u);
        float k1z = __uint_as_float(kv1.z << 16), v1z = __uint_as_float(kv1.z & 0xffff0000u);
        float k1w = __uint_as_float(kv1.w << 16), v1w = __uint_as_float(kv1.w & 0xffff0000u);

        float p0 = q.x * k0x + q.y * k0y + q.z * k0z + q.w * k0w;
        float p1 = q.x * k1x + q.y * k1y + q.z * k1z + q.w * k1w;
        p0 += __shfl_xor(p0, 1);   p1 += __shfl_xor(p1, 1);
        p0 += __shfl_xor(p0, 2);   p1 += __shfl_xor(p1, 2);
        p0 += __shfl_xor(p0, 4);   p1 += __shfl_xor(p1, 4);

        float w0 = __expf(fminf(fmaxf(p0, -10.f), 10.f) + f0);
        float w1 = __expf(fminf(fmaxf(p1, -10.f), 10.f) + f1);
        norm += w0 + w1;
        ax += w0 * v0x + w1 * v1x;
        ay += w0 * v0y + w1 * v1y;
        az += w0 * v0z + w1 * v1z;
        aw += w0 * v0w + w1 * v1w;
    }
    if (i < cnt) {
        int c0 = csrCols[s + i];
        uint4 kv0 = ((const uint4*)KV)[(size_t)c0 * 32 + lane];
        float f0 = filt[c0 * HEAD + h];
        float k0x = __uint_as_float(kv0.x << 16), v0x = __uint_as_float(kv0.x & 0xffff0000u);
        float k0y = __uint_as_float(kv0.y << 16), v0y = __uint_as_float(kv0.y & 0xffff0000u);
        float k0z = __uint_as_float(kv0.z << 16), v0z = __uint_as_float(kv0.z & 0xffff0000u);
        float k0w = __uint_as_float(kv0.w << 16), v0w = __uint_as_float(kv0.w & 0xffff0000u);
        float p0 = q.x * k0x + q.y * k0y + q.z * k0z + q.w * k0w;
        p0 += __shfl_xor(p0, 1);
        p0 += __shfl_xor(p0, 2);
        p0 += __shfl_xor(p0, 4);
        float w0 = __expf(fminf(fmaxf(p0, -10.f), 10.f) + f0);
        norm += w0;
        ax += w0 * v0x; ay += w0 * v0y; az += w0 * v0z; aw += w0 * v0w;
    }
    float inv = 1.0f / (norm + 1e-8f);
    ((float4*)(out + (size_t)node * 128))[lane] =
        make_float4(ax * inv, ay * inv, az * inv, aw * inv);
}

// ---------------------------------------------------------------------------
extern "C" void kernel_launch(void* const* d_in, const int* in_sizes, int n_in,
                              void* d_out, int out_size, void* d_ws, size_t ws_size,
                              hipStream_t stream) {
    const float* embeds = (const float*)d_in[0];
    const float* qT     = (const float*)d_in[1];
    const float* kT     = (const float*)d_in[2];
    const float* vT     = (const float*)d_in[3];
    const float* filt   = (const float*)d_in[4];
    const int*   rows   = (const int*)d_in[5];
    const int*   cols   = (const int*)d_in[6];
    float*       out    = (float*)d_out;

    // Workspace: Q: N*128 f32 | KV: N*128 u32 | counts,starts,cursor: N i32 |
    //            csrCols: E i32 | state: 128 u32
    float*    Q  = (float*)d_ws;
    unsigned* KV = (unsigned*)(Q + (size_t)N_NODES * 128);
    int* counts    = (int*)(KV + (size_t)N_NODES * 128);
    int* starts    = counts + N_NODES;
    int* cursor    = starts + N_NODES;
    int* csrCols   = cursor + N_NODES;
    unsigned* state = (unsigned*)(csrCols + E_EDGES);

    // Split-bf16 weight planes ALIAS the csrCols region (192 KiB of 2.34 MiB).
    // Stream-ordered safe: wprep+qkv complete before scatter writes csrCols.
    unsigned short* WThi = (unsigned short*)csrCols;          // 96 KiB
    unsigned short* WTlo = WThi + 3 * 128 * 128;              // 96 KiB

    wprep_kernel<<<SCAN_NB, 256, 0, stream>>>(qT, kT, vT, WThi, WTlo, counts, state);
    qkv_mfma_kernel<<<(N_NODES + 127) / 128, 512, 0, stream>>>(
        embeds, WThi, WTlo, rows, counts, Q, KV);
    scan_lb_kernel<<<SCAN_NB, 256, 0, stream>>>(counts, starts, cursor, state);
    scatter_kernel<<<(E_EDGES + 255) / 256, 256, 0, stream>>>(rows, cols, cursor, csrCols);
    att_agg_kernel<<<(N_NODES + 7) / 8, 256, 0, stream>>>(
        Q, KV, filt, starts, counts, csrCols, out);
}

// Round 6
// 271.681 us; speedup vs baseline: 1.2622x; 1.0028x over previous
//
#include <hip/hip_runtime.h>

#define N_NODES 100000
#define E_EDGES 600000
#define LATDIM 128
#define HEAD 4
#define HDIM 32

#define SCAN_NB 98          // 98 blocks x 1024 elems >= N_NODES

typedef __bf16 bf16x8 __attribute__((ext_vector_type(8)));
typedef float  f32x4  __attribute__((ext_vector_type(4)));

__device__ __forceinline__ unsigned f32_to_bf16_rne(float x) {
    unsigned u = __float_as_uint(x);
    u += 0x7fffu + ((u >> 16) & 1u);   // round to nearest even
    return u >> 16;
}

__device__ __forceinline__ void bf16_split(float x, unsigned& hi, unsigned& lo) {
    unsigned hb = f32_to_bf16_rne(x);
    float hf = __uint_as_float(hb << 16);
    unsigned lb = f32_to_bf16_rne(x - hf);
    hi = hb; lo = lb;
}

// ---------------------------------------------------------------------------
// Weight prep + workspace zeroing (folds the memset + scan-state init).
// W[k][c] f32 -> WT_hi/WT_lo[m][c][k] bf16 (split precision).
// ---------------------------------------------------------------------------
__global__ __launch_bounds__(256) void wprep_kernel(
    const float* __restrict__ qT, const float* __restrict__ kT,
    const float* __restrict__ vT,
    unsigned short* __restrict__ WThi, unsigned short* __restrict__ WTlo,
    int* __restrict__ counts, unsigned* __restrict__ state)
{
    int g = blockIdx.x * 256 + threadIdx.x;      // 0..25087

    // zero counts (graph replays => must re-zero every launch)
    for (int i = g; i < N_NODES; i += SCAN_NB * 256) counts[i] = 0;
    if (g < 128) state[g] = 0u;

    if (g >= 3072) return;
    int m    = g >> 10;          // 0..2
    int rem  = g & 1023;
    int c    = rem >> 3;         // 0..127
    int k0   = (rem & 7) * 16;   // 0..112
    const float* W = (m == 0) ? qT : (m == 1) ? kT : vT;

    unsigned short hi[16], lo[16];
    #pragma unroll
    for (int j = 0; j < 16; ++j) {
        float x = W[(size_t)(k0 + j) * 128 + c];
        unsigned hb, lb;
        bf16_split(x, hb, lb);
        hi[j] = (unsigned short)hb;
        lo[j] = (unsigned short)lb;
    }
    size_t off = (size_t)m * 16384 + (size_t)c * 128 + k0;
    *(uint4*)(WThi + off)     = *(const uint4*)&hi[0];
    *(uint4*)(WThi + off + 8) = *(const uint4*)&hi[8];
    *(uint4*)(WTlo + off)     = *(const uint4*)&lo[0];
    *(uint4*)(WTlo + off + 8) = *(const uint4*)&lo[8];
}

// ---------------------------------------------------------------------------
// Kernel A (MFMA): fused per-node Q/K/V transform, split-precision bf16
// (ah*bh + al*bh + ah*bl ~ fp32). v6:
//  - 256 thr / 64 nodes per block, B single-buffered overlaying A: 32 KiB LDS
//  - amdgpu_waves_per_eu(2,4): max=4 stops the allocator's 8-waves/EU
//    VGPR-64 squeeze that spilled in r4/r5 (WRITE_SIZE 113-118 MB vs 102)
//  - 4 blocks/CU (VGPR<=128), independent 4-wave barrier groups
//  - fused edge histogram moved to the TAIL: its 600k atomics previously
//    drained at the first barrier (implicit vmcnt(0)) before any MFMA
// ---------------------------------------------------------------------------
__global__ __launch_bounds__(256)
__attribute__((amdgpu_waves_per_eu(2, 4)))
void qkv_mfma_kernel(
    const float* __restrict__ embeds,
    const unsigned short* __restrict__ WThi,
    const unsigned short* __restrict__ WTlo,
    const int* __restrict__ rows,
    int* __restrict__ counts,
    float* __restrict__ Q, unsigned* __restrict__ KV)
{
    __shared__ __align__(16) char smem[32768];
    char* Ahi = smem;              // 16 KiB: 64 rows x 256B   (phase 1)
    char* Alo = smem + 16384;
    char* Bhi = smem;              // 16 KiB: 64 cols x 256B   (phase 2+, overlays A)
    char* Blo = smem + 16384;

    const int tid = threadIdx.x;
    const int rowBase = blockIdx.x * 64;

    uint4 pbh0, pbh1, pbh2, pbh3;      // named scalars: cannot be promoted
    uint4 pbl0, pbl1, pbl2, pbl3;

#define PF(MN, HN) do {                                                          \
        const char* _sh = (const char*)(WThi + (size_t)(MN) * 16384 + (size_t)(HN) * 8192); \
        const char* _sl = (const char*)(WTlo + (size_t)(MN) * 16384 + (size_t)(HN) * 8192); \
        pbh0 = *(const uint4*)(_sh + (size_t)(0 * 256 + tid) * 16);              \
        pbh1 = *(const uint4*)(_sh + (size_t)(1 * 256 + tid) * 16);              \
        pbh2 = *(const uint4*)(_sh + (size_t)(2 * 256 + tid) * 16);              \
        pbh3 = *(const uint4*)(_sh + (size_t)(3 * 256 + tid) * 16);              \
        pbl0 = *(const uint4*)(_sl + (size_t)(0 * 256 + tid) * 16);              \
        pbl1 = *(const uint4*)(_sl + (size_t)(1 * 256 + tid) * 16);              \
        pbl2 = *(const uint4*)(_sl + (size_t)(2 * 256 + tid) * 16);              \
        pbl3 = *(const uint4*)(_sl + (size_t)(3 * 256 + tid) * 16);              \
    } while (0)

#define COMMIT() do {                                                            \
        { int _i = 0 * 256 + tid; int _c = _i >> 4;                              \
          int _s = (_c * 256 + (_i & 15) * 16) ^ ((_c & 7) << 4);                \
          *(uint4*)(Bhi + _s) = pbh0; *(uint4*)(Blo + _s) = pbl0; }              \
        { int _i = 1 * 256 + tid; int _c = _i >> 4;                              \
          int _s = (_c * 256 + (_i & 15) * 16) ^ ((_c & 7) << 4);                \
          *(uint4*)(Bhi + _s) = pbh1; *(uint4*)(Blo + _s) = pbl1; }              \
        { int _i = 2 * 256 + tid; int _c = _i >> 4;                              \
          int _s = (_c * 256 + (_i & 15) * 16) ^ ((_c & 7) << 4);                \
          *(uint4*)(Bhi + _s) = pbh2; *(uint4*)(Blo + _s) = pbl2; }              \
        { int _i = 3 * 256 + tid; int _c = _i >> 4;                              \
          int _s = (_c * 256 + (_i & 15) * 16) ^ ((_c & 7) << 4);                \
          *(uint4*)(Bhi + _s) = pbh3; *(uint4*)(Blo + _s) = pbl3; }              \
    } while (0)

#define MFMA_PANEL(ACC) do {                                                     \
        _Pragma("unroll")                                                        \
        for (int kk = 0; kk < 4; ++kk) {                                         \
            _Pragma("unroll")                                                    \
            for (int n = 0; n < 4; ++n) {                                        \
                int brow = n * 16 + lrow;                                        \
                int byte = brow * 256 + kk * 64 + kg * 16;                       \
                int swz  = byte ^ ((lrow & 7) << 4);                             \
                bf16x8 bh = __builtin_bit_cast(bf16x8, *(const uint4*)(Bhi + swz)); \
                bf16x8 bl = __builtin_bit_cast(bf16x8, *(const uint4*)(Blo + swz)); \
                ACC[n] = __builtin_amdgcn_mfma_f32_16x16x32_bf16(a_hi[kk], bh, ACC[n], 0, 0, 0); \
                ACC[n] = __builtin_amdgcn_mfma_f32_16x16x32_bf16(a_lo[kk], bh, ACC[n], 0, 0, 0); \
                ACC[n] = __builtin_amdgcn_mfma_f32_16x16x32_bf16(a_hi[kk], bl, ACC[n], 0, 0, 0); \
            }                                                                    \
        }                                                                        \
    } while (0)

#define ZACC(ACC) f32x4 ACC[4] = { {0.f,0.f,0.f,0.f}, {0.f,0.f,0.f,0.f},         \
                                   {0.f,0.f,0.f,0.f}, {0.f,0.f,0.f,0.f} }

#define STORE_Q(ACC, H) do {                                                     \
        _Pragma("unroll")                                                        \
        for (int n = 0; n < 4; ++n)                                              \
        _Pragma("unroll")                                                        \
        for (int j = 0; j < 4; ++j) {                                            \
            int gr  = rowBase + wv * 16 + orow + j;                              \
            int col = (H) * 64 + n * 16 + lrow;                                  \
            if (gr < N_NODES) Q[(size_t)gr * 128 + col] = ACC[n][j];             \
        }                                                                        \
    } while (0)

#define STORE_KV(ACC, H) do {                                                    \
        _Pragma("unroll")                                                        \
        for (int n = 0; n < 4; ++n)                                              \
        _Pragma("unroll")                                                        \
        for (int j = 0; j < 4; ++j) {                                            \
            int gr  = rowBase + wv * 16 + orow + j;                              \
            int col = (H) * 64 + n * 16 + lrow;                                  \
            if (gr < N_NODES) {                                                  \
                unsigned pk = f32_to_bf16_rne(kreg[n][j])                        \
                            | (f32_to_bf16_rne(ACC[n][j]) << 16);                \
                KV[(size_t)gr * 128 + col] = pk;                                 \
            }                                                                    \
        }                                                                        \
    } while (0)

    // ---- prefetch B(panel 0 = m0,h0): overlaps the whole A-stage ----
    PF(0, 0);

    // ---- stage A: load embeds f32, split to bf16 hi/lo, swizzled LDS ----
    #pragma unroll
    for (int it = 0; it < 8; ++it) {
        int idx = it * 256 + tid;          // 0..2047 float4 chunks
        int r  = idx >> 5;                 // 0..63
        int c4 = idx & 31;                 // 0..31
        int gr = rowBase + r;
        float4 v = make_float4(0.f, 0.f, 0.f, 0.f);
        if (gr < N_NODES) v = ((const float4*)embeds)[(size_t)gr * 32 + c4];
        unsigned hx, lx, hy, ly, hz, lz, hw, lw;
        bf16_split(v.x, hx, lx); bf16_split(v.y, hy, ly);
        bf16_split(v.z, hz, lz); bf16_split(v.w, hw, lw);
        uint2 hp = make_uint2(hx | (hy << 16), hz | (hw << 16));
        uint2 lp = make_uint2(lx | (ly << 16), lz | (lw << 16));
        int byte = r * 256 + c4 * 8;
        int swz  = byte ^ ((r & 7) << 4);
        *(uint2*)(Ahi + swz) = hp;
        *(uint2*)(Alo + swz) = lp;
    }
    __syncthreads();

    const int lane = tid & 63;
    const int wv   = tid >> 6;         // 0..3 (wave -> 16-row tile)
    const int lrow = lane & 15;
    const int kg   = lane >> 4;        // 0..3 (k-group of MFMA operand)
    const int arow = wv * 16 + lrow;   // 0..63
    const int orow = kg << 2;          // C/D row base within 16-row tile

    // ---- hoist A fragments (one-time; A LDS is dead afterwards) ----
    bf16x8 a_hi[4], a_lo[4];
    #pragma unroll
    for (int kk = 0; kk < 4; ++kk) {
        int byte = arow * 256 + kk * 64 + kg * 16;
        int swz  = byte ^ ((lrow & 7) << 4);     // (arow&7)==(lrow&7)
        a_hi[kk] = __builtin_bit_cast(bf16x8, *(const uint4*)(Ahi + swz));
        a_lo[kk] = __builtin_bit_cast(bf16x8, *(const uint4*)(Alo + swz));
    }
    __syncthreads();           // all waves done reading A -> B may overlay

    COMMIT();                  // B(m0,h0) into LDS (loads have long landed)
    __syncthreads();

    f32x4 kreg[4];

    // ---- panel (m0,h0): Q, h=0 ----
    {
        PF(1, 0);
        ZACC(acc);
        MFMA_PANEL(acc);
        STORE_Q(acc, 0);
        __syncthreads(); COMMIT(); __syncthreads();
    }
    // ---- panel (m1,h0): K kept in regs ----
    {
        PF(2, 0);
        ZACC(acc);
        MFMA_PANEL(acc);
        kreg[0] = acc[0]; kreg[1] = acc[1]; kreg[2] = acc[2]; kreg[3] = acc[3];
        __syncthreads(); COMMIT(); __syncthreads();
    }
    // ---- panel (m2,h0): V -> pack KV, h=0 ----
    {
        PF(0, 1);
        ZACC(acc);
        MFMA_PANEL(acc);
        STORE_KV(acc, 0);
        __syncthreads(); COMMIT(); __syncthreads();
    }
    // ---- panel (m0,h1): Q, h=1 ----
    {
        PF(1, 1);
        ZACC(acc);
        MFMA_PANEL(acc);
        STORE_Q(acc, 1);
        __syncthreads(); COMMIT(); __syncthreads();
    }
    // ---- panel (m1,h1): K kept in regs ----
    {
        PF(2, 1);
        ZACC(acc);
        MFMA_PANEL(acc);
        kreg[0] = acc[0]; kreg[1] = acc[1]; kreg[2] = acc[2]; kreg[3] = acc[3];
        __syncthreads(); COMMIT(); __syncthreads();
    }
    // ---- panel (m2,h1): V -> pack KV, h=1 (no prefetch) ----
    {
        ZACC(acc);
        MFMA_PANEL(acc);
        STORE_KV(acc, 1);
    }

    // ---- fused edge histogram at the TAIL: fire-and-forget atomics
    //      overlap the epilogue + dispatch drain (no barrier follows) ----
    for (int e = blockIdx.x * 256 + tid; e < E_EDGES; e += gridDim.x * 256)
        atomicAdd(&counts[rows[e]], 1);

#undef PF
#undef COMMIT
#undef MFMA_PANEL
#undef ZACC
#undef STORE_Q
#undef STORE_KV
}

// ---------------------------------------------------------------------------
// Single-pass exclusive scan with decoupled lookback (replaces scan1/2/3).
// 98 blocks <= 256 CUs -> all co-resident; state word = (sum<<2)|st,
// st: 0=invalid 1=aggregate 2=inclusive-prefix. Device-scope atomics.
// ---------------------------------------------------------------------------
__global__ __launch_bounds__(256) void scan_lb_kernel(
    const int* __restrict__ counts, int* __restrict__ starts,
    int* __restrict__ cursor, unsigned* __restrict__ state)
{
    __shared__ int s[256];
    __shared__ int bcast;
    int b = blockIdx.x, t = threadIdx.x;
    int base = b * 1024 + t * 4;
    int v0 = (base + 0 < N_NODES) ? counts[base + 0] : 0;
    int v1 = (base + 1 < N_NODES) ? counts[base + 1] : 0;
    int v2 = (base + 2 < N_NODES) ? counts[base + 2] : 0;
    int v3 = (base + 3 < N_NODES) ? counts[base + 3] : 0;
    int local = v0 + v1 + v2 + v3;
    s[t] = local;
    __syncthreads();
    for (int off = 1; off < 256; off <<= 1) {
        int x = (t >= off) ? s[t - off] : 0;
        __syncthreads();
        s[t] += x;
        __syncthreads();
    }
    int incl  = s[t];
    int excl  = incl - local;
    int total = s[255];

    if (t == 0) {
        int sum = 0;
        if (b == 0) {
            atomicExch(&state[0], ((unsigned)total << 2) | 2u);
        } else {
            atomicExch(&state[b], ((unsigned)total << 2) | 1u);
            int i = b - 1;
            while (true) {
                unsigned w = atomicAdd(&state[i], 0u);   // atomic load
                unsigned st = w & 3u;
                if (st == 0u) continue;                  // spin: not published
                sum += (int)(w >> 2);
                if (st == 2u) break;                     // found a prefix
                --i;                                     // aggregate: keep walking
            }
            atomicExch(&state[b], ((unsigned)(sum + total) << 2) | 2u);
        }
        bcast = sum;
    }
    __syncthreads();
    int e = excl + bcast;
    if (base + 0 < N_NODES) { starts[base + 0] = e;                cursor[base + 0] = e; }
    if (base + 1 < N_NODES) { starts[base + 1] = e + v0;           cursor[base + 1] = e + v0; }
    if (base + 2 < N_NODES) { starts[base + 2] = e + v0 + v1;      cursor[base + 2] = e + v0 + v1; }
    if (base + 3 < N_NODES) { starts[base + 3] = e + v0 + v1 + v2; cursor[base + 3] = e + v0 + v1 + v2; }
}

__global__ __launch_bounds__(256) void scatter_kernel(
    const int* __restrict__ rows, const int* __restrict__ cols,
    int* __restrict__ cursor, int* __restrict__ csrCols)
{
    int e = blockIdx.x * 256 + threadIdx.x;
    if (e >= E_EDGES) return;
    int pos = atomicAdd(&cursor[rows[e]], 1);
    csrCols[pos] = cols[e];
}

// ---------------------------------------------------------------------------
// Kernel B: fused attention + aggregation.
// 32 threads/node, 4 dims/thread (uint4 KV load = 16B/lane).
// ---------------------------------------------------------------------------
__global__ __launch_bounds__(256) void att_agg_kernel(
    const float* __restrict__ Q, const unsigned* __restrict__ KV,
    const float* __restrict__ filt,
    const int* __restrict__ starts, const int* __restrict__ counts,
    const int* __restrict__ csrCols,
    float* __restrict__ out)
{
    int t = threadIdx.x;
    int node = blockIdx.x * 8 + (t >> 5);
    if (node >= N_NODES) return;
    int lane = t & 31;           // lane within node group
    int h = lane >> 3;           // head = (lane*4)>>5

    float4 q = ((const float4*)(Q + (size_t)node * 128))[lane];
    int s   = starts[node];
    int cnt = counts[node];

    float norm = 0.f;
    float ax = 0.f, ay = 0.f, az = 0.f, aw = 0.f;

    int i = 0;
    for (; i + 2 <= cnt; i += 2) {
        int c0 = csrCols[s + i];
        int c1 = csrCols[s + i + 1];
        uint4 kv0 = ((const uint4*)KV)[(size_t)c0 * 32 + lane];
        uint4 kv1 = ((const uint4*)KV)[(size_t)c1 * 32 + lane];
        float f0 = filt[c0 * HEAD + h];
        float f1 = filt[c1 * HEAD + h];

        float k0x = __uint_as_float(kv0.x << 16), v0x = __uint_as_float(kv0.x & 0xffff0000u);
        float k0y = __uint_as_float(kv0.y << 16), v0y = __uint_as_float(kv0.y & 0xffff0000u);
        float k0z = __uint_as_float(kv0.z << 16), v0z = __uint_as_float(kv0.z & 0xffff0000u);
        float k0w = __uint_as_float(kv0.w << 16), v0w = __uint_as_float(kv0.w & 0xffff0000u);
        float k1x = __uint_as_float(kv1.x << 16), v1x = __uint_as_float(kv1.x & 0xffff0000u);
        float k1y = __uint_as_float(kv1.y << 16), v1y = __uint_as_float(kv1.y & 0xffff0000u);
        float k1z = __uint_as_float(kv1.z << 16), v1z = __uint_as_float(kv1.z & 0xffff0000u);
        float k1w = __uint_as_float(kv1.w << 16), v1w = __uint_as_float(kv1.w & 0xffff0000u);

        float p0 = q.x * k0x + q.y * k0y + q.z * k0z + q.w * k0w;
        float p1 = q.x * k1x + q.y * k1y + q.z * k1z + q.w * k1w;
        p0 += __shfl_xor(p0, 1);   p1 += __shfl_xor(p1, 1);
        p0 += __shfl_xor(p0, 2);   p1 += __shfl_xor(p1, 2);
        p0 += __shfl_xor(p0, 4);   p1 += __shfl_xor(p1, 4);

        float w0 = __expf(fminf(fmaxf(p0, -10.f), 10.f) + f0);
        float w1 = __expf(fminf(fmaxf(p1, -10.f), 10.f) + f1);
        norm += w0 + w1;
        ax += w0 * v0x + w1 * v1x;
        ay += w0 * v0y + w1 * v1y;
        az += w0 * v0z + w1 * v1z;
        aw += w0 * v0w + w1 * v1w;
    }
    if (i < cnt) {
        int c0 = csrCols[s + i];
        uint4 kv0 = ((const uint4*)KV)[(size_t)c0 * 32 + lane];
        float f0 = filt[c0 * HEAD + h];
        float k0x = __uint_as_float(kv0.x << 16), v0x = __uint_as_float(kv0.x & 0xffff0000u);
        float k0y = __uint_as_float(kv0.y << 16), v0y = __uint_as_float(kv0.y & 0xffff0000u);
        float k0z = __uint_as_float(kv0.z << 16), v0z = __uint_as_float(kv0.z & 0xffff0000u);
        float k0w = __uint_as_float(kv0.w << 16), v0w = __uint_as_float(kv0.w & 0xffff0000u);
        float p0 = q.x * k0x + q.y * k0y + q.z * k0z + q.w * k0w;
        p0 += __shfl_xor(p0, 1);
        p0 += __shfl_xor(p0, 2);
        p0 += __shfl_xor(p0, 4);
        float w0 = __expf(fminf(fmaxf(p0, -10.f), 10.f) + f0);
        norm += w0;
        ax += w0 * v0x; ay += w0 * v0y; az += w0 * v0z; aw += w0 * v0w;
    }
    float inv = 1.0f / (norm + 1e-8f);
    ((float4*)(out + (size_t)node * 128))[lane] =
        make_float4(ax * inv, ay * inv, az * inv, aw * inv);
}

// ---------------------------------------------------------------------------
extern "C" void kernel_launch(void* const* d_in, const int* in_sizes, int n_in,
                              void* d_out, int out_size, void* d_ws, size_t ws_size,
                              hipStream_t stream) {
    const float* embeds = (const float*)d_in[0];
    const float* qT     = (const float*)d_in[1];
    const float* kT     = (const float*)d_in[2];
    const float* vT     = (const float*)d_in[3];
    const float* filt   = (const float*)d_in[4];
    const int*   rows   = (const int*)d_in[5];
    const int*   cols   = (const int*)d_in[6];
    float*       out    = (float*)d_out;

    // Workspace: Q: N*128 f32 | KV: N*128 u32 | counts,starts,cursor: N i32 |
    //            csrCols: E i32 | state: 128 u32
    float*    Q  = (float*)d_ws;
    unsigned* KV = (unsigned*)(Q + (size_t)N_NODES * 128);
    int* counts    = (int*)(KV + (size_t)N_NODES * 128);
    int* starts    = counts + N_NODES;
    int* cursor    = starts + N_NODES;
    int* csrCols   = cursor + N_NODES;
    unsigned* state = (unsigned*)(csrCols + E_EDGES);

    // Split-bf16 weight planes ALIAS the csrCols region (192 KiB of 2.34 MiB).
    // Stream-ordered safe: wprep+qkv complete before scatter writes csrCols.
    unsigned short* WThi = (unsigned short*)csrCols;          // 96 KiB
    unsigned short* WTlo = WThi + 3 * 128 * 128;              // 96 KiB

    wprep_kernel<<<SCAN_NB, 256, 0, stream>>>(qT, kT, vT, WThi, WTlo, counts, state);
    qkv_mfma_kernel<<<(N_NODES + 63) / 64, 256, 0, stream>>>(
        embeds, WThi, WTlo, rows, counts, Q, KV);
    scan_lb_kernel<<<SCAN_NB, 256, 0, stream>>>(counts, starts, cursor, state);
    scatter_kernel<<<(E_EDGES + 255) / 256, 256, 0, stream>>>(rows, cols, cursor, csrCols);
    att_agg_kernel<<<(N_NODES + 7) / 8, 256, 0, stream>>>(
        Q, KV, filt, starts, counts, csrCols, out);
}